// Round 13
// baseline (846.718 us; speedup 1.0000x reference)
//
#include <hip/hip_runtime.h>
#include <cstdint>
#include <cstddef>

typedef _Float16 f16;
typedef f16   f16x4 __attribute__((ext_vector_type(4)));
typedef f16   f16x8 __attribute__((ext_vector_type(8)));
typedef float f32x4 __attribute__((ext_vector_type(4)));

#define MFMA16x32(a, b, c) __builtin_amdgcn_mfma_f32_16x16x32_f16((a), (b), (c), 0, 0, 0)
#define MFMA16x16(a, b, c) __builtin_amdgcn_mfma_f32_16x16x16f16((a), (b), (c), 0, 0, 0)

// async global->LDS, 16B per lane; lds base wave-uniform, global addr per-lane
__device__ __forceinline__ void gload_lds16(const void* g, void* l) {
    __builtin_amdgcn_global_load_lds(
        (const __attribute__((address_space(1))) unsigned int*)g,
        (__attribute__((address_space(3))) unsigned int*)l, 16, 0, 0);
}

// ---------------- prep: f32 -> f16 copy-cast (8 elems/thread) ----------------
__global__ void cvt_f32_f16(const float* __restrict__ in, f16* __restrict__ out, int n8) {
    int i = blockIdx.x * blockDim.x + threadIdx.x;
    if (i >= n8) return;
    const float4 a = ((const float4*)in)[i * 2];
    const float4 b = ((const float4*)in)[i * 2 + 1];
    f16x8 o;
    o[0] = (f16)a.x; o[1] = (f16)a.y; o[2] = (f16)a.z; o[3] = (f16)a.w;
    o[4] = (f16)b.x; o[5] = (f16)b.y; o[6] = (f16)b.z; o[7] = (f16)b.w;
    *(f16x8*)(out + (size_t)i * 8) = o;
}

// ---------------- avg partial reduce: out = (out + (f32)s0) / 16 ----------------
__global__ void avg_reduce(const f16* __restrict__ s0, float* __restrict__ out, int n8) {
    int i = blockIdx.x * blockDim.x + threadIdx.x;
    if (i >= n8) return;
    const f16x8 s = *(const f16x8*)(s0 + (size_t)i * 8);
    float4 a = ((const float4*)out)[i * 2];
    float4 b = ((const float4*)out)[i * 2 + 1];
    const float k = 1.f / 16.f;
    a.x = (a.x + (float)s[0]) * k; a.y = (a.y + (float)s[1]) * k;
    a.z = (a.z + (float)s[2]) * k; a.w = (a.w + (float)s[3]) * k;
    b.x = (b.x + (float)s[4]) * k; b.y = (b.y + (float)s[5]) * k;
    b.z = (b.z + (float)s[6]) * k; b.w = (b.w + (float)s[7]) * k;
    ((float4*)out)[i * 2] = a;
    ((float4*)out)[i * 2 + 1] = b;
}

// ---------------- QKV projection GEMM ----------------
// q epilogue scale = 0.125 * log2(e): scores then use exp2 directly.
__global__ __launch_bounds__(256, 3)
void gemm_qkv(const f16* __restrict__ A, const f16* __restrict__ B,
              const float* __restrict__ bq, const float* __restrict__ bk,
              const float* __restrict__ bv,
              f16* __restrict__ q_sp, f16* __restrict__ k_sp, f16* __restrict__ v_sp)
{
    __shared__ f16 Al[128 * 32];
    __shared__ f16 Bl[128 * 32];
    const int tid = threadIdx.x, lane = tid & 63, w = tid >> 6;
    const int wm = w >> 1, wn = w & 1;
    const int m0 = blockIdx.y * 128, n0 = blockIdx.x * 128;
    const int l15 = lane & 15, lh = lane >> 4;

    f32x4 acc[4][4] = {};

    const int c0 = w, c1 = w + 4;
    const int srow0 = c0 * 16 + (lane >> 2);
    const int srow1 = c1 * 16 + (lane >> 2);
    const int scol = (lane & 3) * 8;

    for (int k0 = 0; k0 < 1024; k0 += 32) {
        gload_lds16(A + (size_t)(m0 + srow0) * 1024 + k0 + scol, &Al[c0 * 512]);
        gload_lds16(A + (size_t)(m0 + srow1) * 1024 + k0 + scol, &Al[c1 * 512]);
        gload_lds16(B + (size_t)(n0 + srow0) * 1024 + k0 + scol, &Bl[c0 * 512]);
        gload_lds16(B + (size_t)(n0 + srow1) * 1024 + k0 + scol, &Bl[c1 * 512]);
        __syncthreads();
        f16x8 af[4], bf[4];
        #pragma unroll
        for (int i = 0; i < 4; ++i) {
            af[i] = *(const f16x8*)&Al[(wm * 64 + i * 16 + l15) * 32 + lh * 8];
            bf[i] = *(const f16x8*)&Bl[(wn * 64 + i * 16 + l15) * 32 + lh * 8];
        }
        #pragma unroll
        for (int i = 0; i < 4; ++i)
            #pragma unroll
            for (int j = 0; j < 4; ++j)
                acc[i][j] = MFMA16x32(af[i], bf[j], acc[i][j]);
        __syncthreads();
    }

    const int seg = n0 >> 10;
    const float* bias = (seg == 0) ? bq : (seg == 1) ? bk : bv;
    f16* dst = (seg == 0) ? q_sp : (seg == 1) ? k_sp : v_sp;
    const float scale = (seg == 0) ? 0.18033688011112042f : 1.0f;  // 0.125*log2(e)

    #pragma unroll
    for (int j = 0; j < 4; ++j) {
        const int n = n0 + wn * 64 + j * 16 + l15;
        const int e = n & 1023, hh = e >> 6, d = e & 63;
        const float bsv = bias[e];
        #pragma unroll
        for (int i = 0; i < 4; ++i) {
            #pragma unroll
            for (int r = 0; r < 4; ++r) {
                const int m = m0 + wm * 64 + i * 16 + lh * 4 + r;
                const int t = m >> 2, bb = m & 3;
                dst[((size_t)(bb * 16 + hh) * 2048 + t) * 64 + d] =
                    (f16)((acc[i][j][r] + bsv) * scale);
            }
        }
    }
}

// ---------------- V pack: [BH][T][HD] -> B-fragment order for 16x16x16 MFMA ----
// Vf[bh][nt][lane][dt][r] = V[nt*16 + (lane>>4)*4 + r][dt*16 + (lane&15)]
__global__ __launch_bounds__(256)
void vpack(const f16* __restrict__ v_sp, f16* __restrict__ vf_) {
    __shared__ f16 L[16 * 64];
    const int nt = blockIdx.x, bh = blockIdx.y;
    const int tid = threadIdx.x;
    const f16* src = v_sp + ((size_t)bh * 2048 + nt * 16) * 64;
    if (tid < 128)
        *(f16x8*)&L[tid * 8] = *(const f16x8*)&src[tid * 8];
    __syncthreads();
    const int lane = tid >> 2, dt = tid & 3;
    const int l15 = lane & 15, lh = lane >> 4;
    f16x4 o;
    #pragma unroll
    for (int r = 0; r < 4; ++r) o[r] = L[(lh * 4 + r) * 64 + dt * 16 + l15];
    *(f16x4*)&vf_[((size_t)bh * 128 + nt) * 1024 + tid * 4] = o;
}

// ---------------- fused attention (LDS-staged, barrier-synced) ----------------
// R12 + ROOT-CAUSE FIX: the PV MFMA transposes the lane->q mapping
// (QK output: q=l15; PV output: q=lh*4+r). R10-R12 multiplied O[q=lh*4+r]
// by inv(q=l15) -> deterministic 6.3e-2 error, identical across sync
// variants. Fix: atomicAdd RAW o; publish invL16[q] (wave0 lanes<16, q=l15);
// apply invL16[idx>>6] at the ctx write where rows are q-indexed.
__global__ __launch_bounds__(512, 2)
void attn_kernel(const f16* __restrict__ q_s, const f16* __restrict__ k_s,
                 const f16* __restrict__ v_f, f16* __restrict__ ctx,
                 float* __restrict__ avg_out, f16* __restrict__ pavg)
{
    __shared__ __align__(16) char Sb[8][8192];      // 64 KB: per-wave 2 x 4KB dbuf
    __shared__ float Oacc[2][1024];                 // 8 KB
    __shared__ float sumL[8][16];
    __shared__ float invL16[16];

    const int tid = threadIdx.x, lane = tid & 63, w = tid >> 6;
    const int g = blockIdx.x & 7, b = g & 3, hz = g >> 2;
    const int t0 = (blockIdx.x >> 3) * 16;
    const int l15 = lane & 15, lh = lane >> 4;

    f16x4 avgv[16] = {};

    Oacc[0][tid] = 0.f; Oacc[0][tid + 512] = 0.f;   // ordered by first barrier below

    char* Swv = &Sb[w][0];

    for (int i = 0; i < 8; ++i) {
        const int h = hz * 8 + i;
        const size_t bh = (size_t)(b * 16 + h);
        const char* Kh = (const char*)(k_s + (bh * 2048 + (size_t)w * 256) * 64);
        const char* Vh = (const char*)(v_f + bh * 131072 + (size_t)w * 16384);
        const f16* Qh = q_s + (bh * 2048 + t0) * 64;
        const f16x8 qa0 = *(const f16x8*)(Qh + l15 * 64 + lh * 8);
        const f16x8 qa1 = *(const f16x8*)(Qh + l15 * 64 + 32 + lh * 8);

        // stage nt=0 into buf0
        gload_lds16(Kh + lane * 16,        Swv);
        gload_lds16(Kh + 1024 + lane * 16, Swv + 1024);
        gload_lds16(Vh + lane * 16,        Swv + 2048);
        gload_lds16(Vh + 1024 + lane * 16, Swv + 3072);
        __syncthreads();                              // chunk 0 landed

        float rsum = 0.f;
        f32x4 o0 = {}, o1 = {}, o2 = {}, o3 = {};
        f16x4 avh[16];

        #pragma unroll
        for (int nt = 0; nt < 16; ++nt) {
            const char* cur = Swv + (nt & 1) * 4096;
            if (nt < 15) {                            // stage nt+1 into other buf
                char* nxt = Swv + ((nt + 1) & 1) * 4096;
                const char* gK = Kh + (size_t)(nt + 1) * 2048;
                const char* gV = Vh + (size_t)(nt + 1) * 2048;
                gload_lds16(gK + lane * 16,        nxt);
                gload_lds16(gK + 1024 + lane * 16, nxt + 1024);
                gload_lds16(gV + lane * 16,        nxt + 2048);
                gload_lds16(gV + 1024 + lane * 16, nxt + 3072);
            }
            // compute chunk nt (data guaranteed by previous barrier)
            const f16x8 kf0 = *(const f16x8*)(cur + l15 * 128 + lh * 16);
            const f16x8 kf1 = *(const f16x8*)(cur + l15 * 128 + lh * 16 + 64);
            f32x4 s = {0.f, 0.f, 0.f, 0.f};
            s = MFMA16x32(kf0, qa0, s);               // swapped: D[key][q] -> lane: q=l15
            s = MFMA16x32(kf1, qa1, s);
            f16x4 tv;
            #pragma unroll
            for (int r = 0; r < 4; ++r) {
                const float e = __builtin_amdgcn_exp2f(s[r]);
                rsum += e;
                tv[r] = (f16)e;
            }
            avh[nt] = tv;                             // unnormalized, q=l15-indexed
            const f16x8 vab = *(const f16x8*)(cur + 2048 + lane * 32);
            const f16x8 vcd = *(const f16x8*)(cur + 2048 + lane * 32 + 16);
            const f16x4 va = __builtin_shufflevector(vab, vab, 0, 1, 2, 3);
            const f16x4 vb = __builtin_shufflevector(vab, vab, 4, 5, 6, 7);
            const f16x4 vc = __builtin_shufflevector(vcd, vcd, 0, 1, 2, 3);
            const f16x4 vd = __builtin_shufflevector(vcd, vcd, 4, 5, 6, 7);
            o0 = MFMA16x16(tv, va, o0);               // out rows q = lh*4+r (!)
            o1 = MFMA16x16(tv, vb, o1);
            o2 = MFMA16x16(tv, vc, o2);
            o3 = MFMA16x16(tv, vd, o3);
            __syncthreads();   // nt+1 staged data landed; cur safe to re-stage
        }

        // ---- cross-wave softmax denominator ----
        rsum += __shfl_xor(rsum, 16);
        rsum += __shfl_xor(rsum, 32);
        if (lane < 16) sumL[w][lane] = rsum;
        __syncthreads();                              // bar1

        Oacc[(i + 1) & 1][tid] = 0.f;                 // zero next head's buffer
        Oacc[(i + 1) & 1][tid + 512] = 0.f;

        float tot = 0.f;
        #pragma unroll
        for (int ww = 0; ww < 8; ++ww) tot += sumL[ww][l15];
        const float inv = 1.f / tot;                  // inv for q = l15
        if (tid < 16) invL16[tid] = inv;              // wave0: l15 == tid
        const f16 hinv = (f16)inv;
        f16x4 hv; hv[0] = hinv; hv[1] = hinv; hv[2] = hinv; hv[3] = hinv;
        #pragma unroll
        for (int nt = 0; nt < 16; ++nt) avgv[nt] += avh[nt] * hv;  // q=l15: inv matches

        float* Ob = &Oacc[i & 1][0];
        #pragma unroll
        for (int r = 0; r < 4; ++r) {
            const int rowb = (lh * 4 + r) * 64;       // row q = lh*4+r
            atomicAdd(&Ob[rowb +      l15], o0[r]);   // RAW (normalize at ctx write)
            atomicAdd(&Ob[rowb + 16 + l15], o1[r]);
            atomicAdd(&Ob[rowb + 32 + l15], o2[r]);
            atomicAdd(&Ob[rowb + 48 + l15], o3[r]);
        }
        __syncthreads();                              // bar2: Oacc + invL16 published

        #pragma unroll
        for (int jj = 0; jj < 2; ++jj) {
            const int idx = tid + jj * 512;
            const int q = idx >> 6, d = idx & 63;
            ctx[((size_t)(t0 + q) * 4 + b) * 1024 + h * 64 + d] =
                (f16)(Ob[idx] * invL16[q]);           // row-correct normalization
        }
    }

    // ---- avg partials: lane owns (q=l15, keys w*256 + nt*16 + lh*4 + r) ----
    if (hz == 0) {
        f16* ao = pavg + ((size_t)b * 2048 + t0 + l15) * 2048 + w * 256 + lh * 4;
        #pragma unroll
        for (int nt = 0; nt < 16; ++nt)
            *(f16x4*)(ao + nt * 16) = avgv[nt];
    } else {
        float* ao = avg_out + ((size_t)b * 2048 + t0 + l15) * 2048 + w * 256 + lh * 4;
        #pragma unroll
        for (int nt = 0; nt < 16; ++nt) {
            float4 v;
            v.x = (float)avgv[nt][0]; v.y = (float)avgv[nt][1];
            v.z = (float)avgv[nt][2]; v.w = (float)avgv[nt][3];
            *(float4*)(ao + nt * 16) = v;
        }
    }
}

// ---------------- output projection GEMM ----------------
__global__ __launch_bounds__(256, 3)
void gemm_out(const f16* __restrict__ A, const f16* __restrict__ B,
              const float* __restrict__ bo, float* __restrict__ out)
{
    __shared__ f16 Al[128 * 32];
    __shared__ f16 Bl[128 * 32];
    const int tid = threadIdx.x, lane = tid & 63, w = tid >> 6;
    const int wm = w >> 1, wn = w & 1;
    const int m0 = blockIdx.y * 128, n0 = blockIdx.x * 128;
    const int l15 = lane & 15, lh = lane >> 4;

    f32x4 acc[4][4] = {};
    const int c0 = w, c1 = w + 4;
    const int srow0 = c0 * 16 + (lane >> 2);
    const int srow1 = c1 * 16 + (lane >> 2);
    const int scol = (lane & 3) * 8;

    for (int k0 = 0; k0 < 1024; k0 += 32) {
        gload_lds16(A + (size_t)(m0 + srow0) * 1024 + k0 + scol, &Al[c0 * 512]);
        gload_lds16(A + (size_t)(m0 + srow1) * 1024 + k0 + scol, &Al[c1 * 512]);
        gload_lds16(B + (size_t)(n0 + srow0) * 1024 + k0 + scol, &Bl[c0 * 512]);
        gload_lds16(B + (size_t)(n0 + srow1) * 1024 + k0 + scol, &Bl[c1 * 512]);
        __syncthreads();
        f16x8 af[4], bf[4];
        #pragma unroll
        for (int i = 0; i < 4; ++i) {
            af[i] = *(const f16x8*)&Al[(wm * 64 + i * 16 + l15) * 32 + lh * 8];
            bf[i] = *(const f16x8*)&Bl[(wn * 64 + i * 16 + l15) * 32 + lh * 8];
        }
        #pragma unroll
        for (int i = 0; i < 4; ++i)
            #pragma unroll
            for (int j = 0; j < 4; ++j)
                acc[i][j] = MFMA16x32(af[i], bf[j], acc[i][j]);
        __syncthreads();
    }

    #pragma unroll
    for (int j = 0; j < 4; ++j) {
        const int n = n0 + wn * 64 + j * 16 + l15;
        const float bsv = bo[n];
        #pragma unroll
        for (int i = 0; i < 4; ++i) {
            #pragma unroll
            for (int r = 0; r < 4; ++r) {
                const int m = m0 + wm * 64 + i * 16 + lh * 4 + r;
                out[(size_t)m * 1024 + n] = acc[i][j][r] + bsv;
            }
        }
    }
}

extern "C" void kernel_launch(void* const* d_in, const int* in_sizes, int n_in,
                              void* d_out, int out_size, void* d_ws, size_t ws_size,
                              hipStream_t stream) {
    const float* query = (const float*)d_in[0];
    const float* wq = (const float*)d_in[1];
    const float* bq = (const float*)d_in[2];
    const float* wk = (const float*)d_in[3];
    const float* bk = (const float*)d_in[4];
    const float* wv = (const float*)d_in[5];
    const float* bv = (const float*)d_in[6];
    const float* wo = (const float*)d_in[7];
    const float* bo = (const float*)d_in[8];
    float* out = (float*)d_out;

    f16* wsh  = (f16*)d_ws;
    f16* Xb   = wsh;                          // 8M  (query f16; later aliased as ctx)
    f16* Wqkv = wsh + (8u << 20);             // 3M
    f16* Wo   = wsh + (11u << 20);            // 1M
    f16* q_sp = wsh + (12u << 20);            // 8M  [B,H,T,HD]
    f16* k_sp = wsh + (20u << 20);            // 8M
    f16* v_sp = wsh + (28u << 20);            // 8M
    f16* v_f  = wsh + (36u << 20);            // 8M  packed B-fragments
    f16* pavg = wsh + (44u << 20);            // 16M f16 = 32MB avg partial (z0)
    f16* ctx  = Xb;

    cvt_f32_f16<<<4096, 256, 0, stream>>>(query, Xb, 1048576);
    cvt_f32_f16<<<512, 256, 0, stream>>>(wq, Wqkv, 131072);
    cvt_f32_f16<<<512, 256, 0, stream>>>(wk, Wqkv + (1u << 20), 131072);
    cvt_f32_f16<<<512, 256, 0, stream>>>(wv, Wqkv + (2u << 20), 131072);
    cvt_f32_f16<<<512, 256, 0, stream>>>(wo, Wo, 131072);

    gemm_qkv<<<dim3(24, 64), 256, 0, stream>>>(Xb, Wqkv, bq, bk, bv, q_sp, k_sp, v_sp);
    vpack<<<dim3(128, 64), 256, 0, stream>>>(v_sp, v_f);
    attn_kernel<<<1024, 512, 0, stream>>>(q_sp, k_sp, v_f, ctx,
                                          out + 8388608 /* avg_attn */, pavg);
    avg_reduce<<<8192, 256, 0, stream>>>(pavg, out + 8388608, 2097152);
    gemm_out<<<dim3(8, 64), 256, 0, stream>>>(ctx, Wo, bo, out);
}